// Round 5
// baseline (148.731 us; speedup 1.0000x reference)
//
#include <hip/hip_runtime.h>

#define B_SZ 8
#define L_SEQ 144
#define NTOK 1152
#define D_MODEL 256
#define D_INNER 512
#define D_STATE 64
#define DT_RANK 4
#define NDBC 132
#define SLAB 152064   // NTOK*NDBC, one split-K slab of dBC

#define BM 64
#define BN 64
#define BK 16

#define CH 16         // scan chunk (tokens)
#define NCH 9         // 144 / 16

// ---------------------------------------------------------------------------
// Tiled GEMM with register prefetch of the next k-slab.
//  A_MK=true : A stored [m][k] (row stride lda) | false: A stored [k][m]
//  B always stored [n][k] (row stride ldb)
//  GN        : guard n<N on B-loads and C-stores (N=132 case)
//  CONV      : (A_MK=false only) A rows are pre-conv xzT[d][tok]; apply
//              depthwise conv(4)+SiLU on the fly while staging to LDS.
//  PERM      : B-row permutation for the dBC producer so that output cols are
//              [dt(4) | B0 C0 B1 C1 ... B63 C63]  (B/C interleaved).
// Split-K: blockIdx.z selects k-slab; C advanced by z*sstride.
// ---------------------------------------------------------------------------
__device__ __forceinline__ int bc_perm(const int p) {
    // stored position p -> original W_x row
    return (p < DT_RANK) ? p
         : (((p - DT_RANK) & 1) ? (DT_RANK + D_STATE + ((p - DT_RANK) >> 1))
                                : (DT_RANK + ((p - DT_RANK) >> 1)));
}

template<bool A_MK, bool GN, bool CONV, bool PERM>
__global__ __launch_bounds__(256) void gemm_k(const float* __restrict__ A,
                                              const float* __restrict__ Bm,
                                              float* __restrict__ C,
                                              const int N, const int lda, const int ldb,
                                              const int ldc,
                                              const float* __restrict__ cw,
                                              const float* __restrict__ cb,
                                              const int kslab, const size_t sstride) {
    __shared__ float As[BK][BM + 4];
    __shared__ float Bs[BK][BN + 4];
    const int tid = threadIdx.x;
    const int m0 = blockIdx.y * BM;
    const int n0 = blockIdx.x * BN;
    const int kbeg = blockIdx.z * kslab;
    const int kend = kbeg + kslab;
    const int ty = tid >> 4, tx = tid & 15;
    const int lrow = tid >> 2, kq = (tid & 3) * 4;   // transpose-load indices
    const int kk = tid >> 4, cc = (tid & 15) * 4;    // direct-load indices
    const int brow = PERM ? bc_perm(n0 + lrow) : (n0 + lrow);
    float acc[4][4] = {};
    float4 av, bv, cw4;
    float xm2 = 0.f, xm1 = 0.f, xp4 = 0.f, cbv = 0.f;

    auto loadA = [&](const int k0) {
        if (A_MK) {
            av = *(const float4*)(A + (size_t)(m0 + lrow) * lda + k0 + kq);
        } else {
            const float* row = A + (size_t)(k0 + kk) * lda + m0 + cc;
            av = *(const float4*)row;
            if (CONV) {
                const int t = (m0 + cc) % L_SEQ;   // tok group base within sequence
                xm2 = (t > 0) ? row[-2] : 0.f;     // t==0: left pad (2 zeros)
                xm1 = (t > 0) ? row[-1] : 0.f;
                xp4 = (t < L_SEQ - 4) ? row[4] : 0.f;  // t==140: right pad (1 zero)
                cw4 = *(const float4*)(cw + (k0 + kk) * 4);
                cbv = cb[k0 + kk];
            }
        }
        if (!GN || (n0 + lrow) < N)
            bv = *(const float4*)(Bm + (size_t)brow * ldb + k0 + kq);
    };

    auto storeLDS = [&]() {
        if (A_MK) {
            As[kq + 0][lrow] = av.x; As[kq + 1][lrow] = av.y;
            As[kq + 2][lrow] = av.z; As[kq + 3][lrow] = av.w;
        } else if (CONV) {
            const float in7[7] = {xm2, xm1, av.x, av.y, av.z, av.w, xp4};
            float4 o;
            float* op = &o.x;
#pragma unroll
            for (int j = 0; j < 4; ++j) {
                float s = cbv;
                s = fmaf(cw4.x, in7[j + 0], s);
                s = fmaf(cw4.y, in7[j + 1], s);
                s = fmaf(cw4.z, in7[j + 2], s);
                s = fmaf(cw4.w, in7[j + 3], s);
                op[j] = s * __builtin_amdgcn_rcpf(1.f + __expf(-s));
            }
            *(float4*)&As[kk][cc] = o;
        } else {
            *(float4*)&As[kk][cc] = av;
        }
        Bs[kq + 0][lrow] = bv.x; Bs[kq + 1][lrow] = bv.y;
        Bs[kq + 2][lrow] = bv.z; Bs[kq + 3][lrow] = bv.w;
    };

    bv = make_float4(0.f, 0.f, 0.f, 0.f);
    loadA(kbeg);
    for (int k0 = kbeg; k0 < kend; k0 += BK) {
        __syncthreads();
        storeLDS();
        __syncthreads();
        if (k0 + BK < kend) loadA(k0 + BK);   // prefetch: regs only, no LDS hazard
#pragma unroll
        for (int k = 0; k < BK; ++k) {
            const float4 a4 = *(const float4*)&As[k][ty * 4];
            const float4 b4 = *(const float4*)&Bs[k][tx * 4];
            const float a_[4] = {a4.x, a4.y, a4.z, a4.w};
            const float b_[4] = {b4.x, b4.y, b4.z, b4.w};
#pragma unroll
            for (int i = 0; i < 4; ++i)
#pragma unroll
                for (int j = 0; j < 4; ++j)
                    acc[i][j] = fmaf(a_[i], b_[j], acc[i][j]);
        }
    }
    C += (size_t)blockIdx.z * sstride;
#pragma unroll
    for (int i = 0; i < 4; ++i) {
        const int gm = m0 + ty * 4 + i;
        const int gn = n0 + tx * 4;
        if (!GN || gn < N)
            *(float4*)(C + (size_t)gm * ldc + gn) =
                make_float4(acc[i][0], acc[i][1], acc[i][2], acc[i][3]);
    }
}

// ---------------------------------------------------------------------------
// gemm3: out[tok][e] = sum_d gT[d][tok] * W_out[e][d]
// Single-pass K=512, no split-K, no reduce. 32x32 tile, BK=32 -> 8x36 = 288
// blocks (same busy-block density as the old split-K grid). Register
// prefetch; 2x2 acc/thread; float2 LDS reads.
// ---------------------------------------------------------------------------
#define BM3 32
#define BN3 32
#define BK3 32
__global__ __launch_bounds__(256) void gemm3_k(const float* __restrict__ A,  // gT [k][m], lda=NTOK
                                               const float* __restrict__ Bw, // W_out [n][k], ldb=512
                                               float* __restrict__ C) {      // out [m][n], ldc=256
    __shared__ float As[BK3][BM3 + 4];
    __shared__ float Bs[BK3][BN3 + 4];
    const int tid = threadIdx.x;
    const int m0 = blockIdx.y * BM3;
    const int n0 = blockIdx.x * BN3;
    const int ak = tid >> 3, am = (tid & 7) << 2;   // A loader: row k, col quad m
    const int bn = tid >> 3, bk = (tid & 7) << 2;   // B loader: row n, k quad
    const int ty = tid >> 4, tx = tid & 15;         // compute: rows ty*2.., cols tx*2..
    float acc[2][2] = {};
    float4 av, bv;

    auto load = [&](const int k0) {
        av = *(const float4*)(A + (size_t)(k0 + ak) * NTOK + m0 + am);
        bv = *(const float4*)(Bw + (size_t)(n0 + bn) * D_INNER + k0 + bk);
    };

    load(0);
    for (int k0 = 0; k0 < D_INNER; k0 += BK3) {
        __syncthreads();
        *(float4*)&As[ak][am] = av;
        Bs[bk + 0][bn] = bv.x; Bs[bk + 1][bn] = bv.y;
        Bs[bk + 2][bn] = bv.z; Bs[bk + 3][bn] = bv.w;
        __syncthreads();
        if (k0 + BK3 < D_INNER) load(k0 + BK3);   // register prefetch
#pragma unroll
        for (int k = 0; k < BK3; ++k) {
            const float2 a2 = *(const float2*)&As[k][ty * 2];
            const float2 b2 = *(const float2*)&Bs[k][tx * 2];
            acc[0][0] = fmaf(a2.x, b2.x, acc[0][0]);
            acc[0][1] = fmaf(a2.x, b2.y, acc[0][1]);
            acc[1][0] = fmaf(a2.y, b2.x, acc[1][0]);
            acc[1][1] = fmaf(a2.y, b2.y, acc[1][1]);
        }
    }
#pragma unroll
    for (int i = 0; i < 2; ++i)
        *(float2*)(C + (size_t)(m0 + ty * 2 + i) * D_MODEL + n0 + tx * 2) =
            make_float2(acc[i][0], acc[i][1]);
}

// ---------------------------------------------------------------------------
// Fused slab-reduce + conv + aux + selective scan.
// Block = 8 waves = 8 d-channels, ONE batch b (all waves share the same dBC
// rows). Per 16-token chunk:
//   stage  (all 512 thr): reduce 4 sl3 slabs' B/C region (16 tok x 128 f,
//           interleaved B0 C0 B1 C1 ...) into LDS -- one float4 per thread.
//   pre-pass (lanes 0..15 of each wave): conv+SiLU recompute, dt 4-slab
//           reduce, delta=softplus, silu(z) -- kept in registers.
//   serial (per wave): 16 iters; ds_read_b64 of (B,C) + readlane broadcasts.
//   reduce : per-wave transposed LDS read (16 lanes x 4 quarters) + 2 shfl_xor.
// Slab reduction is left-associated -> bitwise == old reduce4_k.
// ---------------------------------------------------------------------------
__device__ __forceinline__ float bcast(const float v, const int i) {
    return __int_as_float(__builtin_amdgcn_readlane(__float_as_int(v), i));
}

__global__ __launch_bounds__(512) void scan_k(const float* __restrict__ sl3,
                                              const float* __restrict__ xzT,
                                              const float* __restrict__ W_dt,
                                              const float* __restrict__ b_dt,
                                              const float* __restrict__ A_log,
                                              const float* __restrict__ Dp,
                                              const float* __restrict__ conv_w,
                                              const float* __restrict__ conv_b,
                                              float* __restrict__ gT) {
    __shared__ float bc[CH][128];      // reduced, interleaved (B,C) for chunk
    __shared__ float P[8][CH][65];     // per-wave h*C scratch
    const int tid = threadIdx.x;
    const int w = tid >> 6, lane = tid & 63;
    const int b = blockIdx.x >> 6, dg = blockIdx.x & 63;   // 8 x 64 blocks
    const int d = (dg << 3) | w;
    const int base = b * L_SEQ;
    const float An2 = -__expf(A_log[(d << 6) + lane]) * 1.44269504088896f;
    const float4 wdt = *(const float4*)(W_dt + (d << 2));
    const float bdt = b_dt[d], dpv = Dp[d];
    const float4 cw4 = *(const float4*)(conv_w + (d << 2));
    const float cbv = conv_b[d];
    const int srow = tid >> 5, scol = (tid & 31) << 2;   // staging indices
    float h = 0.f;

    for (int c = 0; c < NCH; ++c) {
        const int t0 = c * CH;
        __syncthreads();   // all waves done reading previous chunk's bc
        {   // stage: reduce 4 slabs of the B/C region into LDS (1 f4/thread)
            const float* q = sl3 + (size_t)(base + t0 + srow) * NDBC + DT_RANK + scol;
            const float4 q0 = *(const float4*)(q);
            const float4 q1 = *(const float4*)(q + SLAB);
            const float4 q2 = *(const float4*)(q + 2 * SLAB);
            const float4 q3 = *(const float4*)(q + 3 * SLAB);
            *(float4*)&bc[srow][scol] =
                make_float4(q0.x + q1.x + q2.x + q3.x, q0.y + q1.y + q2.y + q3.y,
                            q0.z + q1.z + q2.z + q3.z, q0.w + q1.w + q2.w + q3.w);
        }
        float delta_r = 0.f, dix_r = 0.f, dpix_r = 0.f, sz_r = 0.f;
        if (lane < CH) {
            const int t = t0 + lane;
            const int tok = base + t;
            // conv(4)+SiLU recompute (bitwise-identical to pre-fusion conv kernel)
            const float* row = xzT + (size_t)d * NTOK + tok;
            float s0 = cbv;
            if (t >= 2) s0 = fmaf(cw4.x, row[-2], s0);
            if (t >= 1) s0 = fmaf(cw4.y, row[-1], s0);
            s0 = fmaf(cw4.z, row[0], s0);
            if (t < L_SEQ - 1) s0 = fmaf(cw4.w, row[1], s0);
            const float ixv = s0 * __builtin_amdgcn_rcpf(1.f + __expf(-s0));
            // dt quad: 4-slab reduce (left-assoc == reduce4_k)
            const float* qd = sl3 + (size_t)tok * NDBC;
            const float4 e0 = *(const float4*)(qd);
            const float4 e1 = *(const float4*)(qd + SLAB);
            const float4 e2 = *(const float4*)(qd + 2 * SLAB);
            const float4 e3 = *(const float4*)(qd + 3 * SLAB);
            float s = fmaf(e0.x + e1.x + e2.x + e3.x, wdt.x, bdt);
            s = fmaf(e0.y + e1.y + e2.y + e3.y, wdt.y, s);
            s = fmaf(e0.z + e1.z + e2.z + e3.z, wdt.z, s);
            s = fmaf(e0.w + e1.w + e2.w + e3.w, wdt.w, s);
            const float delta = fmaxf(s, 0.f) + __logf(1.f + __expf(-fabsf(s)));
            const float zv = xzT[(size_t)(D_INNER + d) * NTOK + tok];
            delta_r = delta;
            dix_r   = delta * ixv;
            dpix_r  = dpv * ixv;
            sz_r    = zv * __builtin_amdgcn_rcpf(1.f + __expf(-zv));
        }
        __syncthreads();   // bc visible to all waves
#pragma unroll
        for (int i = 0; i < CH; ++i) {
            const float2 bcv = *(const float2*)&bc[i][lane << 1];  // (B,C), LDS
            const float dlt = bcast(delta_r, i);
            const float dxv = bcast(dix_r, i);
            const float dA = __builtin_amdgcn_exp2f(dlt * An2);    // exp(delta*A)
            h = fmaf(dA, h, dxv * bcv.x);
            P[w][i][lane] = h * bcv.y;
        }
        // transposed reduce: token tl = lane&15, state-quarter q = lane>>4
        const int tl = lane & 15, qq = lane >> 4;
        float s2 = 0.f;
#pragma unroll
        for (int j = 0; j < 16; ++j) s2 += P[w][tl][(qq << 4) + j];
        s2 += __shfl_xor(s2, 16, 64);
        s2 += __shfl_xor(s2, 32, 64);
        if (lane < CH)
            gT[(size_t)d * NTOK + base + t0 + lane] = (s2 + dpix_r) * sz_r;
    }
}

// ---------------------------------------------------------------------------
extern "C" void kernel_launch(void* const* d_in, const int* in_sizes, int n_in,
                              void* d_out, int out_size, void* d_ws, size_t ws_size,
                              hipStream_t stream) {
    const float* x      = (const float*)d_in[0];
    // d_in[1] = lastin (unused: reference starts from h0 = 0)
    const float* W_in   = (const float*)d_in[2];
    const float* conv_w = (const float*)d_in[3];
    const float* conv_b = (const float*)d_in[4];
    const float* W_x    = (const float*)d_in[5];
    const float* W_dt   = (const float*)d_in[6];
    const float* b_dt   = (const float*)d_in[7];
    const float* A_log  = (const float*)d_in[8];
    const float* Dp     = (const float*)d_in[9];
    const float* W_out  = (const float*)d_in[10];
    float* out = (float*)d_out;

    float* ws  = (float*)d_ws;
    float* xzT = ws;                    // [1024][1152] = 1,179,648 f
    float* sl3 = xzT + 1179648;         // 4 x [1152][132] = 608,256 f
    float* gT  = sl3 + 4 * SLAB;        // [512][1152]  =   589,824 f

    // 1) xzT[e][tok] = W_in[e][:] · x[tok][:]   (M=1024, N=1152, K=256)
    gemm_k<true, false, false, false><<<dim3(18, 16, 1), 256, 0, stream>>>(
        W_in, x, xzT, NTOK, D_MODEL, D_MODEL, NTOK, nullptr, nullptr, D_MODEL, 0);
    // 2) sl3[z][tok][p] = silu(conv(xz))[tok][:] · W_x[perm(p)][:]
    //    (conv fused in A-load; B/C cols interleaved)  M=1152, N=132, K=512, split-K=4
    gemm_k<false, true, true, true><<<dim3(3, 18, 4), 256, 0, stream>>>(
        xzT, W_x, sl3, NDBC, NTOK, D_INNER, NDBC, conv_w, conv_b, 128, (size_t)SLAB);
    // 3) fused slab-reduce + conv + aux + selective scan -> gT[d][tok]
    scan_k<<<dim3(B_SZ * 64), 512, 0, stream>>>(sl3, xzT, W_dt, b_dt, A_log, Dp,
                                                conv_w, conv_b, gT);
    // 4) out[tok][e] = g[tok][:] · W_out[e][:]  (M=1152, N=256, K=512) single-pass
    gemm3_k<<<dim3(8, 36), 256, 0, stream>>>(gT, W_out, out);
}

// Round 6
// 139.428 us; speedup vs baseline: 1.0667x; 1.0667x over previous
//
#include <hip/hip_runtime.h>

#define B_SZ 8
#define L_SEQ 144
#define NTOK 1152
#define D_MODEL 256
#define D_INNER 512
#define D_STATE 64
#define DT_RANK 4
#define NDBC 132
#define SLAB 152064      // NTOK*NDBC: one split-K slab of dBC
#define XZSLAB 1179648   // 1024*NTOK: one split-K slab of xz

#define BM 64
#define BN 64
#define BK 16

// ---------------------------------------------------------------------------
// Tiled GEMM with register prefetch of the next k-slab.
//  A_MK=true : A stored [m][k] (row stride lda) | false: A stored [k][m]
//  B always stored [n][k] (row stride ldb)
//  GN        : guard n<N on B-loads and C-stores (N=132 case)
//  CONV      : (A_MK=false only) A rows are pre-conv xz[d][tok]; apply
//              depthwise conv(4)+SiLU on the fly while staging to LDS.
//  PERM      : B-row permutation for the dBC producer so output cols are
//              [dt(4) | B0 C0 B1 C1 ... B63 C63]  (B/C interleaved).
//  A2S       : A is split into 2 k-slabs (stride a2off); sum on load.
//              (conv is linear in xz, so sum-then-conv is exact.)
// Split-K: blockIdx.z selects k-slab; C advanced by z*sstride.
// ---------------------------------------------------------------------------
__device__ __forceinline__ int bc_perm(const int p) {
    // stored position p -> original W_x row
    return (p < DT_RANK) ? p
         : (((p - DT_RANK) & 1) ? (DT_RANK + D_STATE + ((p - DT_RANK) >> 1))
                                : (DT_RANK + ((p - DT_RANK) >> 1)));
}

template<bool A_MK, bool GN, bool CONV, bool PERM, bool A2S>
__global__ __launch_bounds__(256) void gemm_k(const float* __restrict__ A,
                                              const float* __restrict__ Bm,
                                              float* __restrict__ C,
                                              const int N, const int lda, const int ldb,
                                              const int ldc,
                                              const float* __restrict__ cw,
                                              const float* __restrict__ cb,
                                              const int kslab, const size_t sstride,
                                              const size_t a2off) {
    __shared__ float As[BK][BM + 4];
    __shared__ float Bs[BK][BN + 4];
    const int tid = threadIdx.x;
    const int m0 = blockIdx.y * BM;
    const int n0 = blockIdx.x * BN;
    const int kbeg = blockIdx.z * kslab;
    const int kend = kbeg + kslab;
    const int ty = tid >> 4, tx = tid & 15;
    const int lrow = tid >> 2, kq = (tid & 3) * 4;   // transpose-load indices
    const int kk = tid >> 4, cc = (tid & 15) * 4;    // direct-load indices
    const int brow = PERM ? bc_perm(n0 + lrow) : (n0 + lrow);
    float acc[4][4] = {};
    float4 av, bv, cw4;
    float xm2 = 0.f, xm1 = 0.f, xp4 = 0.f, cbv = 0.f;

    auto loadA = [&](const int k0) {
        if (A_MK) {
            av = *(const float4*)(A + (size_t)(m0 + lrow) * lda + k0 + kq);
        } else {
            const float* row = A + (size_t)(k0 + kk) * lda + m0 + cc;
            av = *(const float4*)row;
            if (A2S) {
                const float4 a2 = *(const float4*)(row + a2off);
                av.x += a2.x; av.y += a2.y; av.z += a2.z; av.w += a2.w;
            }
            if (CONV) {
                const int t = (m0 + cc) % L_SEQ;   // tok group base within sequence
                xm2 = (t > 0) ? row[-2] : 0.f;     // t==0: left pad (2 zeros)
                xm1 = (t > 0) ? row[-1] : 0.f;
                xp4 = (t < L_SEQ - 4) ? row[4] : 0.f;  // t==140: right pad (1 zero)
                if (A2S) {
                    if (t > 0) { xm2 += row[a2off - 2]; xm1 += row[a2off - 1]; }
                    if (t < L_SEQ - 4) xp4 += row[a2off + 4];
                }
                cw4 = *(const float4*)(cw + (k0 + kk) * 4);
                cbv = cb[k0 + kk];
            }
        }
        if (!GN || (n0 + lrow) < N)
            bv = *(const float4*)(Bm + (size_t)brow * ldb + k0 + kq);
    };

    auto storeLDS = [&]() {
        if (A_MK) {
            As[kq + 0][lrow] = av.x; As[kq + 1][lrow] = av.y;
            As[kq + 2][lrow] = av.z; As[kq + 3][lrow] = av.w;
        } else if (CONV) {
            const float in7[7] = {xm2, xm1, av.x, av.y, av.z, av.w, xp4};
            float4 o;
            float* op = &o.x;
#pragma unroll
            for (int j = 0; j < 4; ++j) {
                float s = cbv;
                s = fmaf(cw4.x, in7[j + 0], s);
                s = fmaf(cw4.y, in7[j + 1], s);
                s = fmaf(cw4.z, in7[j + 2], s);
                s = fmaf(cw4.w, in7[j + 3], s);
                op[j] = s * __builtin_amdgcn_rcpf(1.f + __expf(-s));
            }
            *(float4*)&As[kk][cc] = o;
        } else {
            *(float4*)&As[kk][cc] = av;
        }
        Bs[kq + 0][lrow] = bv.x; Bs[kq + 1][lrow] = bv.y;
        Bs[kq + 2][lrow] = bv.z; Bs[kq + 3][lrow] = bv.w;
    };

    bv = make_float4(0.f, 0.f, 0.f, 0.f);
    loadA(kbeg);
    for (int k0 = kbeg; k0 < kend; k0 += BK) {
        __syncthreads();
        storeLDS();
        __syncthreads();
        if (k0 + BK < kend) loadA(k0 + BK);   // prefetch: regs only, no LDS hazard
#pragma unroll
        for (int k = 0; k < BK; ++k) {
            const float4 a4 = *(const float4*)&As[k][ty * 4];
            const float4 b4 = *(const float4*)&Bs[k][tx * 4];
            const float a_[4] = {a4.x, a4.y, a4.z, a4.w};
            const float b_[4] = {b4.x, b4.y, b4.z, b4.w};
#pragma unroll
            for (int i = 0; i < 4; ++i)
#pragma unroll
                for (int j = 0; j < 4; ++j)
                    acc[i][j] = fmaf(a_[i], b_[j], acc[i][j]);
        }
    }
    C += (size_t)blockIdx.z * sstride;
#pragma unroll
    for (int i = 0; i < 4; ++i) {
        const int gm = m0 + ty * 4 + i;
        const int gn = n0 + tx * 4;
        if (!GN || gn < N)
            *(float4*)(C + (size_t)gm * ldc + gn) =
                make_float4(acc[i][0], acc[i][1], acc[i][2], acc[i][3]);
    }
}

// ---------------------------------------------------------------------------
// Split-K slab reduction: out[i] = sum_{s<8} in[i + s*s4], float4-wide,
// left-associated.
// ---------------------------------------------------------------------------
__global__ __launch_bounds__(256) void reduce8_k(const float4* __restrict__ in,
                                                 float4* __restrict__ out,
                                                 const int n4, const int s4) {
    const int i = blockIdx.x * 256 + threadIdx.x;
    if (i >= n4) return;
    float4 a = in[i];
#pragma unroll
    for (int s = 1; s < 8; ++s) {
        const float4 b = in[i + s * s4];
        a.x += b.x; a.y += b.y; a.z += b.z; a.w += b.w;
    }
    out[i] = a;
}

// ---------------------------------------------------------------------------
// Fused aux+scan (R4-verified form). One wave per (b,d); lane = state n.
//   pre-pass (lane t < CNT): conv+SiLU recompute from the 2 xz slabs (summed),
//     delta=softplus(dt·Wdt+b), silu(z) -- kept in the owning lane's registers.
//   serial : per token i, one dwordx2 load of interleaved (B,C); delta and
//     delta*ix broadcast from lane i via v_readlane (VALU, not LDS pipe).
//   reduce : transposed LDS row-sum (half-row per lane + shfl_xor 32)
// No __syncthreads: each wave owns its own P LDS slice.
// ---------------------------------------------------------------------------
__device__ __forceinline__ float bcast(const float v, const int i) {
    return __int_as_float(__builtin_amdgcn_readlane(__float_as_int(v), i));
}

template<int CNT>
__device__ __forceinline__ void scan_chunk(const float* __restrict__ dBC,
                                           const float* __restrict__ xz,
                                           float* __restrict__ gT,
                                           float (*__restrict__ Pw)[65],
                                           const int d, const int base, const int t0,
                                           const float An2, const float4 wdt,
                                           const float bdt, const float dpv,
                                           const float4 cw4, const float cbv,
                                           const int lane, float& h) {
    float delta_r = 0.f, dix_r = 0.f, dpix_r = 0.f, sz_r = 0.f;
    if (lane < CNT) {
        const int t = t0 + lane;
        const int tok = base + t;
        // conv(4)+SiLU on summed xz slabs (conv linear in xz: exact)
        const float* row = xz + (size_t)d * NTOK + tok;
        float s0 = cbv;
        if (t >= 2) s0 = fmaf(cw4.x, row[-2] + row[XZSLAB - 2], s0);
        if (t >= 1) s0 = fmaf(cw4.y, row[-1] + row[XZSLAB - 1], s0);
        s0 = fmaf(cw4.z, row[0] + row[XZSLAB], s0);
        if (t < L_SEQ - 1) s0 = fmaf(cw4.w, row[1] + row[XZSLAB + 1], s0);
        const float ixv = s0 * __builtin_amdgcn_rcpf(1.f + __expf(-s0));

        const float4 dt4 = *(const float4*)(dBC + (size_t)tok * NDBC);
        float s = fmaf(dt4.x, wdt.x, bdt);
        s = fmaf(dt4.y, wdt.y, s);
        s = fmaf(dt4.z, wdt.z, s);
        s = fmaf(dt4.w, wdt.w, s);
        const float delta = fmaxf(s, 0.f) + __logf(1.f + __expf(-fabsf(s)));
        const float* zp = xz + (size_t)(D_INNER + d) * NTOK + tok;
        const float zv = zp[0] + zp[XZSLAB];
        delta_r = delta;
        dix_r   = delta * ixv;
        dpix_r  = dpv * ixv;
        sz_r    = zv * __builtin_amdgcn_rcpf(1.f + __expf(-zv));
    }
#pragma unroll
    for (int i = 0; i < CNT; ++i) {
        // interleaved (B,C) pair for state n=lane: one 8B coalesced load, L2-hot
        const float2 bc = *(const float2*)(dBC + (size_t)(base + t0 + i) * NDBC
                                           + DT_RANK + 2 * lane);
        const float dlt = bcast(delta_r, i);
        const float dxv = bcast(dix_r, i);
        const float dA = __builtin_amdgcn_exp2f(dlt * An2);        // exp(delta*A)
        h = fmaf(dA, h, dxv * bc.x);
        Pw[i][lane] = h * bc.y;
    }
    const int tl = lane & 31, hf = lane >> 5;
    float s2 = 0.f;
    if (tl < CNT) {
#pragma unroll
        for (int j = 0; j < 32; ++j) s2 += Pw[tl][hf * 32 + j];    // 2-way banks: free
    }
    s2 += __shfl_xor(s2, 32, 64);
    if (hf == 0 && tl < CNT) {
        // lane == tl owns token tl's epilogue registers
        gT[(size_t)d * NTOK + base + t0 + tl] = (s2 + dpix_r) * sz_r;  // coalesced
    }
}

__global__ __launch_bounds__(256) void scan_k(const float* __restrict__ dBC,
                                              const float* __restrict__ xz,
                                              const float* __restrict__ W_dt,
                                              const float* __restrict__ b_dt,
                                              const float* __restrict__ A_log,
                                              const float* __restrict__ Dp,
                                              const float* __restrict__ conv_w,
                                              const float* __restrict__ conv_b,
                                              float* __restrict__ gT) {
    __shared__ float P[4][32][65];
    const int w = threadIdx.x >> 6, lane = threadIdx.x & 63;
    const int b = blockIdx.x >> 7, dg = blockIdx.x & 127;
    const int d = (dg << 2) | w;
    const int base = b * L_SEQ;
    const float An2 = -__expf(A_log[(d << 6) + lane]) * 1.44269504088896f;
    const float4 wdt = *(const float4*)(W_dt + (d << 2));
    const float bdt = b_dt[d], dpv = Dp[d];
    const float4 cw4 = *(const float4*)(conv_w + (d << 2));
    const float cbv = conv_b[d];
    float h = 0.f;
    scan_chunk<32>(dBC, xz, gT, P[w], d, base, 0,   An2, wdt, bdt, dpv, cw4, cbv, lane, h);
    scan_chunk<32>(dBC, xz, gT, P[w], d, base, 32,  An2, wdt, bdt, dpv, cw4, cbv, lane, h);
    scan_chunk<32>(dBC, xz, gT, P[w], d, base, 64,  An2, wdt, bdt, dpv, cw4, cbv, lane, h);
    scan_chunk<32>(dBC, xz, gT, P[w], d, base, 96,  An2, wdt, bdt, dpv, cw4, cbv, lane, h);
    scan_chunk<16>(dBC, xz, gT, P[w], d, base, 128, An2, wdt, bdt, dpv, cw4, cbv, lane, h);
}

// ---------------------------------------------------------------------------
extern "C" void kernel_launch(void* const* d_in, const int* in_sizes, int n_in,
                              void* d_out, int out_size, void* d_ws, size_t ws_size,
                              hipStream_t stream) {
    const float* x      = (const float*)d_in[0];
    // d_in[1] = lastin (unused: reference starts from h0 = 0)
    const float* W_in   = (const float*)d_in[2];
    const float* conv_w = (const float*)d_in[3];
    const float* conv_b = (const float*)d_in[4];
    const float* W_x    = (const float*)d_in[5];
    const float* W_dt   = (const float*)d_in[6];
    const float* b_dt   = (const float*)d_in[7];
    const float* A_log  = (const float*)d_in[8];
    const float* Dp     = (const float*)d_in[9];
    const float* W_out  = (const float*)d_in[10];
    float* out = (float*)d_out;

    float* ws  = (float*)d_ws;
    float* xz  = ws;                    // 2 x [1024][1152] = 2,359,296 f (split-K=2)
    float* dBC = xz + 2 * XZSLAB;       // [1152][132]  =   152,064 f (B/C interleaved)
    float* gT  = dBC + 152064;          // [512][1152]  =   589,824 f
    float* sl3 = gT + 589824;           // 8 x 152,064  = 1,216,512 f
    float* sl6 = ws;                    // reuse: xz dead after scan (8 x 294,912 = 2,359,296 fits exactly)

    // 1) xz[z][e][tok] = W_in[e][k-slab z] · x[tok][k-slab z]
    //    (M=1024, N=1152, K=256) split-K=2 -> 576 blocks; slabs summed by consumers
    gemm_k<true, false, false, false, false><<<dim3(18, 16, 2), 256, 0, stream>>>(
        W_in, x, xz, NTOK, D_MODEL, D_MODEL, NTOK, nullptr, nullptr, 128,
        (size_t)XZSLAB, 0);
    // 2) sl3[z][tok][p] = silu(conv(xz0+xz1))[tok][:] · W_x[perm(p)][:]
    //    (conv fused in A-load; B/C cols interleaved)  M=1152, N=132, K=512,
    //    split-K=8 -> 432 blocks
    gemm_k<false, true, true, true, true><<<dim3(3, 18, 8), 256, 0, stream>>>(
        xz, W_x, sl3, NDBC, NTOK, D_INNER, NDBC, conv_w, conv_b, 64, (size_t)SLAB,
        (size_t)XZSLAB);
    reduce8_k<<<dim3(149), 256, 0, stream>>>((const float4*)sl3, (float4*)dBC,
                                             NTOK * NDBC / 4, NTOK * NDBC / 4);
    // 3) fused conv + aux + selective scan -> gT[d][tok]
    scan_k<<<dim3(B_SZ * 128), 256, 0, stream>>>(dBC, xz, W_dt, b_dt, A_log, Dp,
                                                 conv_w, conv_b, gT);
    // 4) out[tok][e] = g[tok][:] · W_out[e][:]  (M=1152, N=256, K=512)
    //    split-K=8 -> 576 blocks
    gemm_k<false, false, false, false, false><<<dim3(4, 18, 8), 256, 0, stream>>>(
        gT, W_out, sl6, D_MODEL, NTOK, D_INNER, D_MODEL, nullptr, nullptr, 64,
        (size_t)NTOK * D_MODEL, 0);
    reduce8_k<<<dim3(288), 256, 0, stream>>>((const float4*)sl6, (float4*)out,
                                             NTOK * D_MODEL / 4, NTOK * D_MODEL / 4);
}

// Round 7
// 136.407 us; speedup vs baseline: 1.0903x; 1.0221x over previous
//
#include <hip/hip_runtime.h>

#define B_SZ 8
#define L_SEQ 144
#define NTOK 1152
#define D_MODEL 256
#define D_INNER 512
#define D_STATE 64
#define DT_RANK 4
#define NDBC 132
#define SLAB 152064      // NTOK*NDBC: one split-K slab of dBC

#define BM 64
#define BN 64
#define BK 16

typedef __attribute__((ext_vector_type(8))) short bf16x8;
typedef __attribute__((ext_vector_type(4))) float f32x4;

// fp32 -> bf16-split (hi = RNE bf16, lo = trunc bf16 of residual), packed
// into int4 pairs for 16B LDS/register traffic.
__device__ __forceinline__ void cvt8(const float4& f0, const float4& f1,
                                     int4& hi, int4& lo) {
    const float f[8] = {f0.x, f0.y, f0.z, f0.w, f1.x, f1.y, f1.z, f1.w};
    unsigned h[8], l[8];
#pragma unroll
    for (int e = 0; e < 8; ++e) {
        const unsigned u = __float_as_uint(f[e]);
        const unsigned t = u + 0x7FFFu + ((u >> 16) & 1u);
        h[e] = t >> 16;
        l[e] = __float_as_uint(f[e] - __uint_as_float(t & 0xFFFF0000u)) >> 16;
    }
    hi = make_int4((int)(h[0] | (h[1] << 16)), (int)(h[2] | (h[3] << 16)),
                   (int)(h[4] | (h[5] << 16)), (int)(h[6] | (h[7] << 16)));
    lo = make_int4((int)(l[0] | (l[1] << 16)), (int)(l[2] | (l[3] << 16)),
                   (int)(l[4] | (l[5] << 16)), (int)(l[6] | (l[7] << 16)));
}

// ---------------------------------------------------------------------------
// gemm1 (MFMA): xz[e][tok] = W_in[e][:] · x[tok][:]   M=1024 N=1152 K=256
// bf16-split-3: D = Ah·Bh + Ah·Bl + Al·Bh, fp32 accumulate.
// Block 64x64, 4 waves (2x2), wave 32x32 = 2x2 16x16 frags. Staging converts
// fp32->bf16 pair into padded LDS (rows +8 pad -> worst 2-way banks, free).
// Fragment convention: operand lane&15 = m/n, k spread over (lane>>4, elem)
// identically for A and B -> any consistent k-order is correct.
// ---------------------------------------------------------------------------
#define LW 40
__global__ __launch_bounds__(256) void gemm1_mfma(const float* __restrict__ W_in,
                                                  const float* __restrict__ x,
                                                  float* __restrict__ xz) {
    __shared__ unsigned short Ah[64][LW], Al[64][LW], Bh[64][LW], Bl[64][LW];
    const int tid = threadIdx.x;
    const int m0 = blockIdx.y * 64, n0 = blockIdx.x * 64;
    const int r = tid >> 2, kq = (tid & 3) * 8;        // staging: row, k-offset
    const int w = tid >> 6, lane = tid & 63;
    const int wm = (w & 1) * 32, wn = (w >> 1) * 32;   // wave tile origin
    const int fr = lane & 15, fk = (lane >> 4) * 8;    // fragment row / k-group
    f32x4 acc[2][2] = {};
    float4 a0, a1, b0, b1;

    auto loadG = [&](const int k0) {
        const float* ap = W_in + (size_t)(m0 + r) * D_MODEL + k0 + kq;
        const float* bp = x    + (size_t)(n0 + r) * D_MODEL + k0 + kq;
        a0 = *(const float4*)ap; a1 = *(const float4*)(ap + 4);
        b0 = *(const float4*)bp; b1 = *(const float4*)(bp + 4);
    };

    loadG(0);
    for (int k0 = 0; k0 < D_MODEL; k0 += 32) {
        int4 hi, lo;
        __syncthreads();
        cvt8(a0, a1, hi, lo);
        *(int4*)&Ah[r][kq] = hi; *(int4*)&Al[r][kq] = lo;
        cvt8(b0, b1, hi, lo);
        *(int4*)&Bh[r][kq] = hi; *(int4*)&Bl[r][kq] = lo;
        __syncthreads();
        if (k0 + 32 < D_MODEL) loadG(k0 + 32);   // register prefetch
        bf16x8 ah[2], al[2], bh[2], bl[2];
#pragma unroll
        for (int i = 0; i < 2; ++i) {
            ah[i] = *(const bf16x8*)&Ah[wm + 16 * i + fr][fk];
            al[i] = *(const bf16x8*)&Al[wm + 16 * i + fr][fk];
            bh[i] = *(const bf16x8*)&Bh[wn + 16 * i + fr][fk];
            bl[i] = *(const bf16x8*)&Bl[wn + 16 * i + fr][fk];
        }
#pragma unroll
        for (int i = 0; i < 2; ++i)
#pragma unroll
            for (int j = 0; j < 2; ++j) {
                acc[i][j] = __builtin_amdgcn_mfma_f32_16x16x32_bf16(ah[i], bh[j], acc[i][j], 0, 0, 0);
                acc[i][j] = __builtin_amdgcn_mfma_f32_16x16x32_bf16(ah[i], bl[j], acc[i][j], 0, 0, 0);
                acc[i][j] = __builtin_amdgcn_mfma_f32_16x16x32_bf16(al[i], bh[j], acc[i][j], 0, 0, 0);
            }
    }
    // C/D layout: col = lane&15, row = (lane>>4)*4 + reg  [guide-verified]
    const int orow = (lane >> 4) * 4;
#pragma unroll
    for (int i = 0; i < 2; ++i)
#pragma unroll
        for (int j = 0; j < 2; ++j)
#pragma unroll
            for (int q = 0; q < 4; ++q)
                xz[(size_t)(m0 + wm + 16 * i + orow + q) * NTOK
                   + n0 + wn + 16 * j + fr] = acc[i][j][q];
}

// ---------------------------------------------------------------------------
// gemm3 (MFMA, direct-from-global): out[tok][e] = g[tok][:] · W_out[e][:]
// M=1152 N=256 K=512, split-K=8 slabs. A = bf16-split g (written by scan),
// B = W_out converted in-register. No LDS. Wave 32x32.
// ---------------------------------------------------------------------------
__global__ __launch_bounds__(256) void gemm3_mfma(const unsigned short* __restrict__ ghi,
                                                  const unsigned short* __restrict__ glo,
                                                  const float* __restrict__ W_out,
                                                  float* __restrict__ slab) {
    const int tid = threadIdx.x;
    const int n0 = blockIdx.x * 64, m0 = blockIdx.y * 64;
    const int kbeg = blockIdx.z * 64;
    const int w = tid >> 6, lane = tid & 63;
    const int wm = (w & 1) * 32, wn = (w >> 1) * 32;
    const int fr = lane & 15, fk = (lane >> 4) * 8;
    f32x4 acc[2][2] = {};
    slab += (size_t)blockIdx.z * (NTOK * D_MODEL);
#pragma unroll
    for (int ks = 0; ks < 2; ++ks) {
        const int k0 = kbeg + ks * 32;
        bf16x8 ah[2], al[2], bh[2], bl[2];
#pragma unroll
        for (int i = 0; i < 2; ++i) {
            const size_t ao = (size_t)(m0 + wm + 16 * i + fr) * D_INNER + k0 + fk;
            ah[i] = *(const bf16x8*)(ghi + ao);
            al[i] = *(const bf16x8*)(glo + ao);
        }
#pragma unroll
        for (int j = 0; j < 2; ++j) {
            const float* bp = W_out + (size_t)(n0 + wn + 16 * j + fr) * D_INNER + k0 + fk;
            int4 hi, lo;
            cvt8(*(const float4*)bp, *(const float4*)(bp + 4), hi, lo);
            bh[j] = *(bf16x8*)&hi;
            bl[j] = *(bf16x8*)&lo;
        }
#pragma unroll
        for (int i = 0; i < 2; ++i)
#pragma unroll
            for (int j = 0; j < 2; ++j) {
                acc[i][j] = __builtin_amdgcn_mfma_f32_16x16x32_bf16(ah[i], bh[j], acc[i][j], 0, 0, 0);
                acc[i][j] = __builtin_amdgcn_mfma_f32_16x16x32_bf16(ah[i], bl[j], acc[i][j], 0, 0, 0);
                acc[i][j] = __builtin_amdgcn_mfma_f32_16x16x32_bf16(al[i], bh[j], acc[i][j], 0, 0, 0);
            }
    }
    const int orow = (lane >> 4) * 4;
#pragma unroll
    for (int i = 0; i < 2; ++i)
#pragma unroll
        for (int j = 0; j < 2; ++j)
#pragma unroll
            for (int q = 0; q < 4; ++q)
                slab[(size_t)(m0 + wm + 16 * i + orow + q) * D_MODEL
                     + n0 + wn + 16 * j + fr] = acc[i][j][q];
}

// ---------------------------------------------------------------------------
// Tiled fp32 GEMM (g2 only): conv-fused, PERM-interleaved B/C, split-K.
// ---------------------------------------------------------------------------
__device__ __forceinline__ int bc_perm(const int p) {
    return (p < DT_RANK) ? p
         : (((p - DT_RANK) & 1) ? (DT_RANK + D_STATE + ((p - DT_RANK) >> 1))
                                : (DT_RANK + ((p - DT_RANK) >> 1)));
}

template<bool A_MK, bool GN, bool CONV, bool PERM>
__global__ __launch_bounds__(256) void gemm_k(const float* __restrict__ A,
                                              const float* __restrict__ Bm,
                                              float* __restrict__ C,
                                              const int N, const int lda, const int ldb,
                                              const int ldc,
                                              const float* __restrict__ cw,
                                              const float* __restrict__ cb,
                                              const int kslab, const size_t sstride) {
    __shared__ float As[BK][BM + 4];
    __shared__ float Bs[BK][BN + 4];
    const int tid = threadIdx.x;
    const int m0 = blockIdx.y * BM;
    const int n0 = blockIdx.x * BN;
    const int kbeg = blockIdx.z * kslab;
    const int kend = kbeg + kslab;
    const int ty = tid >> 4, tx = tid & 15;
    const int lrow = tid >> 2, kq = (tid & 3) * 4;
    const int kk = tid >> 4, cc = (tid & 15) * 4;
    const int brow = PERM ? bc_perm(n0 + lrow) : (n0 + lrow);
    float acc[4][4] = {};
    float4 av, bv, cw4;
    float xm2 = 0.f, xm1 = 0.f, xp4 = 0.f, cbv = 0.f;

    auto loadA = [&](const int k0) {
        if (A_MK) {
            av = *(const float4*)(A + (size_t)(m0 + lrow) * lda + k0 + kq);
        } else {
            const float* row = A + (size_t)(k0 + kk) * lda + m0 + cc;
            av = *(const float4*)row;
            if (CONV) {
                const int t = (m0 + cc) % L_SEQ;
                xm2 = (t > 0) ? row[-2] : 0.f;
                xm1 = (t > 0) ? row[-1] : 0.f;
                xp4 = (t < L_SEQ - 4) ? row[4] : 0.f;
                cw4 = *(const float4*)(cw + (k0 + kk) * 4);
                cbv = cb[k0 + kk];
            }
        }
        if (!GN || (n0 + lrow) < N)
            bv = *(const float4*)(Bm + (size_t)brow * ldb + k0 + kq);
    };

    auto storeLDS = [&]() {
        if (A_MK) {
            As[kq + 0][lrow] = av.x; As[kq + 1][lrow] = av.y;
            As[kq + 2][lrow] = av.z; As[kq + 3][lrow] = av.w;
        } else if (CONV) {
            const float in7[7] = {xm2, xm1, av.x, av.y, av.z, av.w, xp4};
            float4 o;
            float* op = &o.x;
#pragma unroll
            for (int j = 0; j < 4; ++j) {
                float s = cbv;
                s = fmaf(cw4.x, in7[j + 0], s);
                s = fmaf(cw4.y, in7[j + 1], s);
                s = fmaf(cw4.z, in7[j + 2], s);
                s = fmaf(cw4.w, in7[j + 3], s);
                op[j] = s * __builtin_amdgcn_rcpf(1.f + __expf(-s));
            }
            *(float4*)&As[kk][cc] = o;
        } else {
            *(float4*)&As[kk][cc] = av;
        }
        Bs[kq + 0][lrow] = bv.x; Bs[kq + 1][lrow] = bv.y;
        Bs[kq + 2][lrow] = bv.z; Bs[kq + 3][lrow] = bv.w;
    };

    bv = make_float4(0.f, 0.f, 0.f, 0.f);
    loadA(kbeg);
    for (int k0 = kbeg; k0 < kend; k0 += BK) {
        __syncthreads();
        storeLDS();
        __syncthreads();
        if (k0 + BK < kend) loadA(k0 + BK);
#pragma unroll
        for (int k = 0; k < BK; ++k) {
            const float4 a4 = *(const float4*)&As[k][ty * 4];
            const float4 b4 = *(const float4*)&Bs[k][tx * 4];
            const float a_[4] = {a4.x, a4.y, a4.z, a4.w};
            const float b_[4] = {b4.x, b4.y, b4.z, b4.w};
#pragma unroll
            for (int i = 0; i < 4; ++i)
#pragma unroll
                for (int j = 0; j < 4; ++j)
                    acc[i][j] = fmaf(a_[i], b_[j], acc[i][j]);
        }
    }
    C += (size_t)blockIdx.z * sstride;
#pragma unroll
    for (int i = 0; i < 4; ++i) {
        const int gm = m0 + ty * 4 + i;
        const int gn = n0 + tx * 4;
        if (!GN || gn < N)
            *(float4*)(C + (size_t)gm * ldc + gn) =
                make_float4(acc[i][0], acc[i][1], acc[i][2], acc[i][3]);
    }
}

// ---------------------------------------------------------------------------
// Split-K slab reduction: out[i] = sum_{s<8} in[i + s*s4], left-associated.
// ---------------------------------------------------------------------------
__global__ __launch_bounds__(256) void reduce8_k(const float4* __restrict__ in,
                                                 float4* __restrict__ out,
                                                 const int n4, const int s4) {
    const int i = blockIdx.x * 256 + threadIdx.x;
    if (i >= n4) return;
    float4 a = in[i];
#pragma unroll
    for (int s = 1; s < 8; ++s) {
        const float4 b = in[i + s * s4];
        a.x += b.x; a.y += b.y; a.z += b.z; a.w += b.w;
    }
    out[i] = a;
}

// ---------------------------------------------------------------------------
// Fused aux+scan (R4-verified structure). One wave per (b,d); lane = state n.
// Epilogue now emits g as a bf16-split pair in [tok][d] layout so gemm3's
// A-fragments are k-contiguous (scattered 2B stores, 16-32 lanes; tiny).
// ---------------------------------------------------------------------------
__device__ __forceinline__ float bcast(const float v, const int i) {
    return __int_as_float(__builtin_amdgcn_readlane(__float_as_int(v), i));
}

template<int CNT>
__device__ __forceinline__ void scan_chunk(const float* __restrict__ dBC,
                                           const float* __restrict__ xz,
                                           unsigned short* __restrict__ ghi,
                                           unsigned short* __restrict__ glo,
                                           float (*__restrict__ Pw)[65],
                                           const int d, const int base, const int t0,
                                           const float An2, const float4 wdt,
                                           const float bdt, const float dpv,
                                           const float4 cw4, const float cbv,
                                           const int lane, float& h) {
    float delta_r = 0.f, dix_r = 0.f, dpix_r = 0.f, sz_r = 0.f;
    if (lane < CNT) {
        const int t = t0 + lane;
        const int tok = base + t;
        const float* row = xz + (size_t)d * NTOK + tok;
        float s0 = cbv;
        if (t >= 2) s0 = fmaf(cw4.x, row[-2], s0);
        if (t >= 1) s0 = fmaf(cw4.y, row[-1], s0);
        s0 = fmaf(cw4.z, row[0], s0);
        if (t < L_SEQ - 1) s0 = fmaf(cw4.w, row[1], s0);
        const float ixv = s0 * __builtin_amdgcn_rcpf(1.f + __expf(-s0));

        const float4 dt4 = *(const float4*)(dBC + (size_t)tok * NDBC);
        float s = fmaf(dt4.x, wdt.x, bdt);
        s = fmaf(dt4.y, wdt.y, s);
        s = fmaf(dt4.z, wdt.z, s);
        s = fmaf(dt4.w, wdt.w, s);
        const float delta = fmaxf(s, 0.f) + __logf(1.f + __expf(-fabsf(s)));
        const float zv = xz[(size_t)(D_INNER + d) * NTOK + tok];
        delta_r = delta;
        dix_r   = delta * ixv;
        dpix_r  = dpv * ixv;
        sz_r    = zv * __builtin_amdgcn_rcpf(1.f + __expf(-zv));
    }
#pragma unroll
    for (int i = 0; i < CNT; ++i) {
        const float2 bc = *(const float2*)(dBC + (size_t)(base + t0 + i) * NDBC
                                           + DT_RANK + 2 * lane);
        const float dlt = bcast(delta_r, i);
        const float dxv = bcast(dix_r, i);
        const float dA = __builtin_amdgcn_exp2f(dlt * An2);
        h = fmaf(dA, h, dxv * bc.x);
        Pw[i][lane] = h * bc.y;
    }
    const int tl = lane & 31, hf = lane >> 5;
    float s2 = 0.f;
    if (tl < CNT) {
#pragma unroll
        for (int j = 0; j < 32; ++j) s2 += Pw[tl][hf * 32 + j];
    }
    s2 += __shfl_xor(s2, 32, 64);
    if (hf == 0 && tl < CNT) {
        const float g = (s2 + dpix_r) * sz_r;
        const unsigned u = __float_as_uint(g);
        const unsigned t = u + 0x7FFFu + ((u >> 16) & 1u);
        const size_t o = (size_t)(base + t0 + tl) * D_INNER + d;
        ghi[o] = (unsigned short)(t >> 16);
        glo[o] = (unsigned short)(__float_as_uint(
                     g - __uint_as_float(t & 0xFFFF0000u)) >> 16);
    }
}

__global__ __launch_bounds__(256) void scan_k(const float* __restrict__ dBC,
                                              const float* __restrict__ xz,
                                              const float* __restrict__ W_dt,
                                              const float* __restrict__ b_dt,
                                              const float* __restrict__ A_log,
                                              const float* __restrict__ Dp,
                                              const float* __restrict__ conv_w,
                                              const float* __restrict__ conv_b,
                                              unsigned short* __restrict__ ghi,
                                              unsigned short* __restrict__ glo) {
    __shared__ float P[4][32][65];
    const int w = threadIdx.x >> 6, lane = threadIdx.x & 63;
    const int b = blockIdx.x >> 7, dg = blockIdx.x & 127;
    const int d = (dg << 2) | w;
    const int base = b * L_SEQ;
    const float An2 = -__expf(A_log[(d << 6) + lane]) * 1.44269504088896f;
    const float4 wdt = *(const float4*)(W_dt + (d << 2));
    const float bdt = b_dt[d], dpv = Dp[d];
    const float4 cw4 = *(const float4*)(conv_w + (d << 2));
    const float cbv = conv_b[d];
    float h = 0.f;
    scan_chunk<32>(dBC, xz, ghi, glo, P[w], d, base, 0,   An2, wdt, bdt, dpv, cw4, cbv, lane, h);
    scan_chunk<32>(dBC, xz, ghi, glo, P[w], d, base, 32,  An2, wdt, bdt, dpv, cw4, cbv, lane, h);
    scan_chunk<32>(dBC, xz, ghi, glo, P[w], d, base, 64,  An2, wdt, bdt, dpv, cw4, cbv, lane, h);
    scan_chunk<32>(dBC, xz, ghi, glo, P[w], d, base, 96,  An2, wdt, bdt, dpv, cw4, cbv, lane, h);
    scan_chunk<16>(dBC, xz, ghi, glo, P[w], d, base, 128, An2, wdt, bdt, dpv, cw4, cbv, lane, h);
}

// ---------------------------------------------------------------------------
extern "C" void kernel_launch(void* const* d_in, const int* in_sizes, int n_in,
                              void* d_out, int out_size, void* d_ws, size_t ws_size,
                              hipStream_t stream) {
    const float* x      = (const float*)d_in[0];
    // d_in[1] = lastin (unused: reference starts from h0 = 0)
    const float* W_in   = (const float*)d_in[2];
    const float* conv_w = (const float*)d_in[3];
    const float* conv_b = (const float*)d_in[4];
    const float* W_x    = (const float*)d_in[5];
    const float* W_dt   = (const float*)d_in[6];
    const float* b_dt   = (const float*)d_in[7];
    const float* A_log  = (const float*)d_in[8];
    const float* Dp     = (const float*)d_in[9];
    const float* W_out  = (const float*)d_in[10];
    float* out = (float*)d_out;

    float* ws  = (float*)d_ws;
    float* xz  = ws;                          // [1024][1152] = 1,179,648 f
    float* dBC = xz + 1179648;                // [1152][132]  =   152,064 f (B/C interleaved)
    float* sl3 = dBC + 152064;                // 8 x 152,064  = 1,216,512 f
    unsigned short* ghi = (unsigned short*)(sl3 + 8 * SLAB);   // [1152][512] bf16-hi
    unsigned short* glo = ghi + NTOK * D_INNER;                // [1152][512] bf16-lo
    float* sl6 = (float*)(glo + NTOK * D_INNER);               // 8 x 294,912 f

    // 1) xz = W_in · x^T   (MFMA bf16-split-3, single-pass K=256)
    gemm1_mfma<<<dim3(18, 16), 256, 0, stream>>>(W_in, x, xz);
    // 2) sl3[z][tok][p] = silu(conv(xz))[tok][:] · W_x[perm(p)][:]
    //    (conv fused in A-load; B/C cols interleaved) split-K=8
    gemm_k<false, true, true, true><<<dim3(3, 18, 8), 256, 0, stream>>>(
        xz, W_x, sl3, NDBC, NTOK, D_INNER, NDBC, conv_w, conv_b, 64, (size_t)SLAB);
    reduce8_k<<<dim3(149), 256, 0, stream>>>((const float4*)sl3, (float4*)dBC,
                                             NTOK * NDBC / 4, NTOK * NDBC / 4);
    // 3) fused conv + aux + scan -> g as bf16-split [tok][d]
    scan_k<<<dim3(B_SZ * 128), 256, 0, stream>>>(dBC, xz, W_dt, b_dt, A_log, Dp,
                                                 conv_w, conv_b, ghi, glo);
    // 4) out = g · W_out^T  (MFMA bf16-split-3, direct-global, split-K=8)
    gemm3_mfma<<<dim3(4, 18, 8), 256, 0, stream>>>(ghi, glo, W_out, sl6);
    reduce8_k<<<dim3(288), 256, 0, stream>>>((const float4*)sl6, (float4*)out,
                                             NTOK * D_MODEL / 4, NTOK * D_MODEL / 4);
}

// Round 8
// 130.453 us; speedup vs baseline: 1.1401x; 1.0456x over previous
//
#include <hip/hip_runtime.h>

#define B_SZ 8
#define L_SEQ 144
#define NTOK 1152
#define D_MODEL 256
#define D_INNER 512
#define D_STATE 64
#define DT_RANK 4
#define NDBC 132
#define SLAB 152064      // NTOK*NDBC: one split-K slab of dBC

typedef __attribute__((ext_vector_type(8))) short bf16x8;
typedef __attribute__((ext_vector_type(4))) float f32x4;

// fp32 -> bf16-split (hi = RNE bf16, lo = trunc bf16 of residual), packed
// into int4 pairs for 16B LDS/register traffic.
__device__ __forceinline__ void cvt8(const float4& f0, const float4& f1,
                                     int4& hi, int4& lo) {
    const float f[8] = {f0.x, f0.y, f0.z, f0.w, f1.x, f1.y, f1.z, f1.w};
    unsigned h[8], l[8];
#pragma unroll
    for (int e = 0; e < 8; ++e) {
        const unsigned u = __float_as_uint(f[e]);
        const unsigned t = u + 0x7FFFu + ((u >> 16) & 1u);
        h[e] = t >> 16;
        l[e] = __float_as_uint(f[e] - __uint_as_float(t & 0xFFFF0000u)) >> 16;
    }
    hi = make_int4((int)(h[0] | (h[1] << 16)), (int)(h[2] | (h[3] << 16)),
                   (int)(h[4] | (h[5] << 16)), (int)(h[6] | (h[7] << 16)));
    lo = make_int4((int)(l[0] | (l[1] << 16)), (int)(l[2] | (l[3] << 16)),
                   (int)(l[4] | (l[5] << 16)), (int)(l[6] | (l[7] << 16)));
}

// unpack 8 packed u32 (hi<<16|lo) into hi/lo bf16x8 fragments
__device__ __forceinline__ void unpack8(const int4& p0, const int4& p1,
                                        bf16x8& hv, bf16x8& lv) {
    const unsigned u[8] = {(unsigned)p0.x, (unsigned)p0.y, (unsigned)p0.z,
                           (unsigned)p0.w, (unsigned)p1.x, (unsigned)p1.y,
                           (unsigned)p1.z, (unsigned)p1.w};
    int h[4], l[4];
#pragma unroll
    for (int i = 0; i < 4; ++i) {
        h[i] = (int)((u[2 * i] >> 16) | (u[2 * i + 1] & 0xFFFF0000u));
        l[i] = (int)((u[2 * i] & 0xFFFFu) | (u[2 * i + 1] << 16));
    }
    hv = *(bf16x8*)h;
    lv = *(bf16x8*)l;
}

// ---------------------------------------------------------------------------
// gemm1 (MFMA): xz[e][tok] = W_in[e][:] · x[tok][:]   M=1024 N=1152 K=256
// bf16-split-3: D = Ah·Bh + Ah·Bl + Al·Bh, fp32 accumulate. (R7-verified)
// ---------------------------------------------------------------------------
#define LW 40
__global__ __launch_bounds__(256) void gemm1_mfma(const float* __restrict__ W_in,
                                                  const float* __restrict__ x,
                                                  float* __restrict__ xz) {
    __shared__ unsigned short Ah[64][LW], Al[64][LW], Bh[64][LW], Bl[64][LW];
    const int tid = threadIdx.x;
    const int m0 = blockIdx.y * 64, n0 = blockIdx.x * 64;
    const int r = tid >> 2, kq = (tid & 3) * 8;        // staging: row, k-offset
    const int w = tid >> 6, lane = tid & 63;
    const int wm = (w & 1) * 32, wn = (w >> 1) * 32;   // wave tile origin
    const int fr = lane & 15, fk = (lane >> 4) * 8;    // fragment row / k-group
    f32x4 acc[2][2] = {};
    float4 a0, a1, b0, b1;

    auto loadG = [&](const int k0) {
        const float* ap = W_in + (size_t)(m0 + r) * D_MODEL + k0 + kq;
        const float* bp = x    + (size_t)(n0 + r) * D_MODEL + k0 + kq;
        a0 = *(const float4*)ap; a1 = *(const float4*)(ap + 4);
        b0 = *(const float4*)bp; b1 = *(const float4*)(bp + 4);
    };

    loadG(0);
    for (int k0 = 0; k0 < D_MODEL; k0 += 32) {
        int4 hi, lo;
        __syncthreads();
        cvt8(a0, a1, hi, lo);
        *(int4*)&Ah[r][kq] = hi; *(int4*)&Al[r][kq] = lo;
        cvt8(b0, b1, hi, lo);
        *(int4*)&Bh[r][kq] = hi; *(int4*)&Bl[r][kq] = lo;
        __syncthreads();
        if (k0 + 32 < D_MODEL) loadG(k0 + 32);   // register prefetch
        bf16x8 ah[2], al[2], bh[2], bl[2];
#pragma unroll
        for (int i = 0; i < 2; ++i) {
            ah[i] = *(const bf16x8*)&Ah[wm + 16 * i + fr][fk];
            al[i] = *(const bf16x8*)&Al[wm + 16 * i + fr][fk];
            bh[i] = *(const bf16x8*)&Bh[wn + 16 * i + fr][fk];
            bl[i] = *(const bf16x8*)&Bl[wn + 16 * i + fr][fk];
        }
#pragma unroll
        for (int i = 0; i < 2; ++i)
#pragma unroll
            for (int j = 0; j < 2; ++j) {
                acc[i][j] = __builtin_amdgcn_mfma_f32_16x16x32_bf16(ah[i], bh[j], acc[i][j], 0, 0, 0);
                acc[i][j] = __builtin_amdgcn_mfma_f32_16x16x32_bf16(ah[i], bl[j], acc[i][j], 0, 0, 0);
                acc[i][j] = __builtin_amdgcn_mfma_f32_16x16x32_bf16(al[i], bh[j], acc[i][j], 0, 0, 0);
            }
    }
    const int orow = (lane >> 4) * 4;   // C/D: col = lane&15, row = (lane>>4)*4+reg
#pragma unroll
    for (int i = 0; i < 2; ++i)
#pragma unroll
        for (int j = 0; j < 2; ++j)
#pragma unroll
            for (int q = 0; q < 4; ++q)
                xz[(size_t)(m0 + wm + 16 * i + orow + q) * NTOK
                   + n0 + wn + 16 * j + fr] = acc[i][j][q];
}

// ---------------------------------------------------------------------------
// gemm2 (MFMA): sl3[z][tok][p] = silu(conv(xz))[tok][:] · W_x[perm(p)][:]
// M=1152(tok) N=132(e,GN-guarded) K=512(d), split-K=8 (2 k-steps of 32).
// A-staging: load xz rows [d][tok]+halo, conv(4)+SiLU (bitwise == previous
// fp32 version's chain), bf16-split, TRANSPOSED 2B writes into [tok][k] LDS.
// B-staging: W_x rows (PERM interleave), cvt8, int4 writes.
// ---------------------------------------------------------------------------
__device__ __forceinline__ int bc_perm(const int p) {
    return (p < DT_RANK) ? p
         : (((p - DT_RANK) & 1) ? (DT_RANK + D_STATE + ((p - DT_RANK) >> 1))
                                : (DT_RANK + ((p - DT_RANK) >> 1)));
}

__global__ __launch_bounds__(256) void gemm2_mfma(const float* __restrict__ xz,
                                                  const float* __restrict__ W_x,
                                                  float* __restrict__ slab,
                                                  const float* __restrict__ cw,
                                                  const float* __restrict__ cb) {
    __shared__ unsigned short Ah[64][LW], Al[64][LW], Bh[64][LW], Bl[64][LW];
    const int tid = threadIdx.x;
    const int n0 = blockIdx.x * 64;      // e-cols (0,64,128)
    const int m0 = blockIdx.y * 64;      // toks
    const int kbeg = blockIdx.z * 64;    // d-slab
    const int ar = tid >> 3, ac8 = (tid & 7) * 8;   // A: d-row, tok-octet
    const int br = tid >> 2, bq8 = (tid & 3) * 8;   // B: e-row, k-octet
    const int brow = bc_perm(n0 + br);   // used only when n0+br < 132
    const int w = tid >> 6, lane = tid & 63;
    const int wm = (w & 1) * 32, wn = (w >> 1) * 32;
    const int fr = lane & 15, fk = (lane >> 4) * 8;
    const int t = (m0 + ac8) % L_SEQ;    // octet never straddles a sequence
    f32x4 acc[2][2] = {};
    slab += (size_t)blockIdx.z * SLAB;

#pragma unroll
    for (int ks = 0; ks < 2; ++ks) {
        const int k0 = kbeg + ks * 32;
        const int d = k0 + ar;
        const float* row = xz + (size_t)d * NTOK + m0 + ac8;
        const float4 a0 = *(const float4*)row;
        const float4 a1 = *(const float4*)(row + 4);
        const float xm2 = (t > 0) ? row[-2] : 0.f;            // left pad
        const float xm1 = (t > 0) ? row[-1] : 0.f;
        const float xp8 = (t < L_SEQ - 8) ? row[8] : 0.f;     // right pad
        const float4 cw4 = *(const float4*)(cw + d * 4);
        const float cbv = cb[d];
        float4 bv0 = make_float4(0.f, 0.f, 0.f, 0.f), bv1 = bv0;
        if (n0 + br < NDBC) {
            const float* bp = W_x + (size_t)brow * D_INNER + k0 + bq8;
            bv0 = *(const float4*)bp; bv1 = *(const float4*)(bp + 4);
        }
        __syncthreads();   // previous step's fragment reads complete
        {
            const float in[11] = {xm2, xm1, a0.x, a0.y, a0.z, a0.w,
                                  a1.x, a1.y, a1.z, a1.w, xp8};
#pragma unroll
            for (int j = 0; j < 8; ++j) {
                float s = cbv;
                s = fmaf(cw4.x, in[j + 0], s);
                s = fmaf(cw4.y, in[j + 1], s);
                s = fmaf(cw4.z, in[j + 2], s);
                s = fmaf(cw4.w, in[j + 3], s);
                const float g = s * __builtin_amdgcn_rcpf(1.f + __expf(-s));
                const unsigned u = __float_as_uint(g);
                const unsigned tt = u + 0x7FFFu + ((u >> 16) & 1u);
                Ah[ac8 + j][ar] = (unsigned short)(tt >> 16);
                Al[ac8 + j][ar] = (unsigned short)(__float_as_uint(
                                     g - __uint_as_float(tt & 0xFFFF0000u)) >> 16);
            }
            int4 hi, lo;
            cvt8(bv0, bv1, hi, lo);
            *(int4*)&Bh[br][bq8] = hi; *(int4*)&Bl[br][bq8] = lo;
        }
        __syncthreads();
        bf16x8 ah[2], al[2], bh[2], bl[2];
#pragma unroll
        for (int i = 0; i < 2; ++i) {
            ah[i] = *(const bf16x8*)&Ah[wm + 16 * i + fr][fk];
            al[i] = *(const bf16x8*)&Al[wm + 16 * i + fr][fk];
            bh[i] = *(const bf16x8*)&Bh[wn + 16 * i + fr][fk];
            bl[i] = *(const bf16x8*)&Bl[wn + 16 * i + fr][fk];
        }
#pragma unroll
        for (int i = 0; i < 2; ++i)
#pragma unroll
            for (int j = 0; j < 2; ++j) {
                acc[i][j] = __builtin_amdgcn_mfma_f32_16x16x32_bf16(ah[i], bh[j], acc[i][j], 0, 0, 0);
                acc[i][j] = __builtin_amdgcn_mfma_f32_16x16x32_bf16(ah[i], bl[j], acc[i][j], 0, 0, 0);
                acc[i][j] = __builtin_amdgcn_mfma_f32_16x16x32_bf16(al[i], bh[j], acc[i][j], 0, 0, 0);
            }
    }
    const int orow = (lane >> 4) * 4;
#pragma unroll
    for (int i = 0; i < 2; ++i)
#pragma unroll
        for (int j = 0; j < 2; ++j) {
            const int gn = n0 + wn + 16 * j + fr;
            if (gn < NDBC)
#pragma unroll
                for (int q = 0; q < 4; ++q)
                    slab[(size_t)(m0 + wm + 16 * i + orow + q) * NDBC + gn]
                        = acc[i][j][q];
        }
}

// ---------------------------------------------------------------------------
// gemm3 (MFMA, direct-from-global): out[tok][e] = g[tok][:] · W_out[e][:]
// M=1152 N=256 K=512, split-K=8. A = packed bf16-split g (u32 hi<<16|lo),
// B = W_out converted in-register. No LDS.
// ---------------------------------------------------------------------------
__global__ __launch_bounds__(256) void gemm3_mfma(const unsigned* __restrict__ gpk,
                                                  const float* __restrict__ W_out,
                                                  float* __restrict__ slab) {
    const int tid = threadIdx.x;
    const int n0 = blockIdx.x * 64, m0 = blockIdx.y * 64;
    const int kbeg = blockIdx.z * 64;
    const int w = tid >> 6, lane = tid & 63;
    const int wm = (w & 1) * 32, wn = (w >> 1) * 32;
    const int fr = lane & 15, fk = (lane >> 4) * 8;
    f32x4 acc[2][2] = {};
    slab += (size_t)blockIdx.z * (NTOK * D_MODEL);
#pragma unroll
    for (int ks = 0; ks < 2; ++ks) {
        const int k0 = kbeg + ks * 32;
        bf16x8 ah[2], al[2], bh[2], bl[2];
#pragma unroll
        for (int i = 0; i < 2; ++i) {
            const unsigned* ap = gpk + (size_t)(m0 + wm + 16 * i + fr) * D_INNER + k0 + fk;
            unpack8(*(const int4*)ap, *(const int4*)(ap + 4), ah[i], al[i]);
        }
#pragma unroll
        for (int j = 0; j < 2; ++j) {
            const float* bp = W_out + (size_t)(n0 + wn + 16 * j + fr) * D_INNER + k0 + fk;
            int4 hi, lo;
            cvt8(*(const float4*)bp, *(const float4*)(bp + 4), hi, lo);
            bh[j] = *(bf16x8*)&hi;
            bl[j] = *(bf16x8*)&lo;
        }
#pragma unroll
        for (int i = 0; i < 2; ++i)
#pragma unroll
            for (int j = 0; j < 2; ++j) {
                acc[i][j] = __builtin_amdgcn_mfma_f32_16x16x32_bf16(ah[i], bh[j], acc[i][j], 0, 0, 0);
                acc[i][j] = __builtin_amdgcn_mfma_f32_16x16x32_bf16(ah[i], bl[j], acc[i][j], 0, 0, 0);
                acc[i][j] = __builtin_amdgcn_mfma_f32_16x16x32_bf16(al[i], bh[j], acc[i][j], 0, 0, 0);
            }
    }
    const int orow = (lane >> 4) * 4;
#pragma unroll
    for (int i = 0; i < 2; ++i)
#pragma unroll
        for (int j = 0; j < 2; ++j)
#pragma unroll
            for (int q = 0; q < 4; ++q)
                slab[(size_t)(m0 + wm + 16 * i + orow + q) * D_MODEL
                     + n0 + wn + 16 * j + fr] = acc[i][j][q];
}

// ---------------------------------------------------------------------------
// Split-K slab reduction: out[i] = sum_{s<8} in[i + s*s4], left-associated.
// ---------------------------------------------------------------------------
__global__ __launch_bounds__(256) void reduce8_k(const float4* __restrict__ in,
                                                 float4* __restrict__ out,
                                                 const int n4, const int s4) {
    const int i = blockIdx.x * 256 + threadIdx.x;
    if (i >= n4) return;
    float4 a = in[i];
#pragma unroll
    for (int s = 1; s < 8; ++s) {
        const float4 b = in[i + s * s4];
        a.x += b.x; a.y += b.y; a.z += b.z; a.w += b.w;
    }
    out[i] = a;
}

// ---------------------------------------------------------------------------
// Fused aux+scan (R4-verified structure). One wave per (b,d); lane = state n.
// Epilogue emits g as ONE packed u32 (bf16 hi<<16 | lo) per token at [tok][d].
// ---------------------------------------------------------------------------
__device__ __forceinline__ float bcast(const float v, const int i) {
    return __int_as_float(__builtin_amdgcn_readlane(__float_as_int(v), i));
}

template<int CNT>
__device__ __forceinline__ void scan_chunk(const float* __restrict__ dBC,
                                           const float* __restrict__ xz,
                                           unsigned* __restrict__ gpk,
                                           float (*__restrict__ Pw)[65],
                                           const int d, const int base, const int t0,
                                           const float An2, const float4 wdt,
                                           const float bdt, const float dpv,
                                           const float4 cw4, const float cbv,
                                           const int lane, float& h) {
    float delta_r = 0.f, dix_r = 0.f, dpix_r = 0.f, sz_r = 0.f;
    if (lane < CNT) {
        const int t = t0 + lane;
        const int tok = base + t;
        const float* row = xz + (size_t)d * NTOK + tok;
        float s0 = cbv;
        if (t >= 2) s0 = fmaf(cw4.x, row[-2], s0);
        if (t >= 1) s0 = fmaf(cw4.y, row[-1], s0);
        s0 = fmaf(cw4.z, row[0], s0);
        if (t < L_SEQ - 1) s0 = fmaf(cw4.w, row[1], s0);
        const float ixv = s0 * __builtin_amdgcn_rcpf(1.f + __expf(-s0));

        const float4 dt4 = *(const float4*)(dBC + (size_t)tok * NDBC);
        float s = fmaf(dt4.x, wdt.x, bdt);
        s = fmaf(dt4.y, wdt.y, s);
        s = fmaf(dt4.z, wdt.z, s);
        s = fmaf(dt4.w, wdt.w, s);
        const float delta = fmaxf(s, 0.f) + __logf(1.f + __expf(-fabsf(s)));
        const float zv = xz[(size_t)(D_INNER + d) * NTOK + tok];
        delta_r = delta;
        dix_r   = delta * ixv;
        dpix_r  = dpv * ixv;
        sz_r    = zv * __builtin_amdgcn_rcpf(1.f + __expf(-zv));
    }
#pragma unroll
    for (int i = 0; i < CNT; ++i) {
        const float2 bc = *(const float2*)(dBC + (size_t)(base + t0 + i) * NDBC
                                           + DT_RANK + 2 * lane);
        const float dlt = bcast(delta_r, i);
        const float dxv = bcast(dix_r, i);
        const float dA = __builtin_amdgcn_exp2f(dlt * An2);
        h = fmaf(dA, h, dxv * bc.x);
        Pw[i][lane] = h * bc.y;
    }
    const int tl = lane & 31, hf = lane >> 5;
    float s2 = 0.f;
    if (tl < CNT) {
#pragma unroll
        for (int j = 0; j < 32; ++j) s2 += Pw[tl][hf * 32 + j];
    }
    s2 += __shfl_xor(s2, 32, 64);
    if (hf == 0 && tl < CNT) {
        const float g = (s2 + dpix_r) * sz_r;
        const unsigned u = __float_as_uint(g);
        const unsigned t = u + 0x7FFFu + ((u >> 16) & 1u);
        const unsigned lo16 = __float_as_uint(
            g - __uint_as_float(t & 0xFFFF0000u)) >> 16;
        gpk[(size_t)(base + t0 + tl) * D_INNER + d] = (t & 0xFFFF0000u) | lo16;
    }
}

__global__ __launch_bounds__(256) void scan_k(const float* __restrict__ dBC,
                                              const float* __restrict__ xz,
                                              const float* __restrict__ W_dt,
                                              const float* __restrict__ b_dt,
                                              const float* __restrict__ A_log,
                                              const float* __restrict__ Dp,
                                              const float* __restrict__ conv_w,
                                              const float* __restrict__ conv_b,
                                              unsigned* __restrict__ gpk) {
    __shared__ float P[4][32][65];
    const int w = threadIdx.x >> 6, lane = threadIdx.x & 63;
    const int b = blockIdx.x >> 7, dg = blockIdx.x & 127;
    const int d = (dg << 2) | w;
    const int base = b * L_SEQ;
    const float An2 = -__expf(A_log[(d << 6) + lane]) * 1.44269504088896f;
    const float4 wdt = *(const float4*)(W_dt + (d << 2));
    const float bdt = b_dt[d], dpv = Dp[d];
    const float4 cw4 = *(const float4*)(conv_w + (d << 2));
    const float cbv = conv_b[d];
    float h = 0.f;
    scan_chunk<32>(dBC, xz, gpk, P[w], d, base, 0,   An2, wdt, bdt, dpv, cw4, cbv, lane, h);
    scan_chunk<32>(dBC, xz, gpk, P[w], d, base, 32,  An2, wdt, bdt, dpv, cw4, cbv, lane, h);
    scan_chunk<32>(dBC, xz, gpk, P[w], d, base, 64,  An2, wdt, bdt, dpv, cw4, cbv, lane, h);
    scan_chunk<32>(dBC, xz, gpk, P[w], d, base, 96,  An2, wdt, bdt, dpv, cw4, cbv, lane, h);
    scan_chunk<16>(dBC, xz, gpk, P[w], d, base, 128, An2, wdt, bdt, dpv, cw4, cbv, lane, h);
}

// ---------------------------------------------------------------------------
extern "C" void kernel_launch(void* const* d_in, const int* in_sizes, int n_in,
                              void* d_out, int out_size, void* d_ws, size_t ws_size,
                              hipStream_t stream) {
    const float* x      = (const float*)d_in[0];
    // d_in[1] = lastin (unused: reference starts from h0 = 0)
    const float* W_in   = (const float*)d_in[2];
    const float* conv_w = (const float*)d_in[3];
    const float* conv_b = (const float*)d_in[4];
    const float* W_x    = (const float*)d_in[5];
    const float* W_dt   = (const float*)d_in[6];
    const float* b_dt   = (const float*)d_in[7];
    const float* A_log  = (const float*)d_in[8];
    const float* Dp     = (const float*)d_in[9];
    const float* W_out  = (const float*)d_in[10];
    float* out = (float*)d_out;

    float* ws  = (float*)d_ws;
    float* xz  = ws;                          // [1024][1152] = 1,179,648 f
    float* dBC = xz + 1179648;                // [1152][132]  =   152,064 f (B/C interleaved)
    float* sl3 = dBC + 152064;                // 8 x 152,064  = 1,216,512 f
    unsigned* gpk = (unsigned*)(sl3 + 8 * SLAB);   // [1152][512] packed bf16 pair
    float* sl6 = (float*)(gpk + NTOK * D_INNER);   // 8 x 294,912 f

    // 1) xz = W_in · x^T   (MFMA bf16-split-3, single-pass K=256)
    gemm1_mfma<<<dim3(18, 16), 256, 0, stream>>>(W_in, x, xz);
    // 2) sl3[z][tok][p] = silu(conv(xz)) · W_x[perm(p)]  (MFMA, conv in staging,
    //    B/C interleave, split-K=8)
    gemm2_mfma<<<dim3(3, 18, 8), 256, 0, stream>>>(xz, W_x, sl3, conv_w, conv_b);
    reduce8_k<<<dim3(149), 256, 0, stream>>>((const float4*)sl3, (float4*)dBC,
                                             NTOK * NDBC / 4, NTOK * NDBC / 4);
    // 3) fused conv + aux + scan -> g packed bf16-split [tok][d]
    scan_k<<<dim3(B_SZ * 128), 256, 0, stream>>>(dBC, xz, W_dt, b_dt, A_log, Dp,
                                                 conv_w, conv_b, gpk);
    // 4) out = g · W_out^T  (MFMA bf16-split-3, direct-global, split-K=8)
    gemm3_mfma<<<dim3(4, 18, 8), 256, 0, stream>>>(gpk, W_out, sl6);
    reduce8_k<<<dim3(288), 256, 0, stream>>>((const float4*)sl6, (float4*)out,
                                             NTOK * D_MODEL / 4, NTOK * D_MODEL / 4);
}